// Round 1
// baseline (316.413 us; speedup 1.0000x reference)
//
#include <hip/hip_runtime.h>
#include <hip/hip_bf16.h>

// Decoder loss: keep-mask (kth-value threshold + local max), BCE coord loss,
// bidirectional NN recolor + L1 rgb loss.
// L = 16384 candidates, N = 10000 targets, K=8 (reduces to argmin; see notes).

#define BT 64      // targets per block in backward scan
#define CCH 2048   // candidate chunk per blockIdx.y
#define CTI 512    // LDS candidate tile
#define ET 64      // empty-candidates per block in forward scan
#define TCH 1024   // target chunk per blockIdx.y
#define TTI 256    // LDS target tile

// ---------------- Kernel 1: keep mask (local max + exact rank select) -------
__global__ __launch_bounds__(256) void k_keep(
    const float* __restrict__ pred, const int* __restrict__ pnum_p,
    int* __restrict__ keep, int L) {
  __shared__ unsigned int lmbits[512];   // L/32 bits, L<=16384
  __shared__ unsigned int hist[256];
  __shared__ unsigned int sel_prefix;
  __shared__ unsigned int sel_rank;
  int tid = threadIdx.x;
  int words = L / 32;
  // per-8-group argmax (first occurrence, matching jnp.argmax)
  for (int w = tid; w < words; w += 256) {
    unsigned int bits = 0;
    for (int g = 0; g < 4; ++g) {
      int base = w * 32 + g * 8;
      float bv = pred[base]; int bi = 0;
      for (int j = 1; j < 8; ++j) {
        float v = pred[base + j];
        if (v > bv) { bv = v; bi = j; }
      }
      bits |= 1u << (g * 8 + bi);
    }
    lmbits[w] = bits;
  }
  if (tid == 0) { sel_prefix = 0u; sel_rank = 0u; }
  __syncthreads();
  int rank = L - pnum_p[0] - 1;   // 0-based rank of threshold element
  // 4-round radix select on monotone uint keys (local-max -> +inf)
  for (int shift = 24; shift >= 0; shift -= 8) {
    for (int b = tid; b < 256; b += 256) hist[b] = 0u;
    __syncthreads();
    unsigned int mask_hi = (shift == 24) ? 0u : (0xFFFFFFFFu << (shift + 8));
    unsigned int pfx = sel_prefix;
    for (int i = tid; i < L; i += 256) {
      bool lm = (lmbits[i >> 5] >> (i & 31)) & 1u;
      unsigned int key;
      if (lm) key = 0xFF800000u;   // map(+inf)
      else {
        unsigned int fb = __float_as_uint(pred[i]);
        key = (fb & 0x80000000u) ? ~fb : (fb | 0x80000000u);
      }
      if ((key & mask_hi) == (pfx & mask_hi))
        atomicAdd(&hist[(key >> shift) & 255u], 1u);
    }
    __syncthreads();
    if (tid == 0) {
      unsigned int r = (shift == 24) ? (unsigned int)rank : sel_rank;
      unsigned int cum = 0, chosen = 0;
      for (int b = 0; b < 256; ++b) {
        unsigned int c = hist[b];
        if (r < cum + c) { chosen = (unsigned int)b; r -= cum; break; }
        cum += c;
      }
      sel_prefix |= chosen << shift;
      sel_rank = r;
    }
    __syncthreads();
  }
  unsigned int key = sel_prefix;
  unsigned int fb = (key & 0x80000000u) ? (key & 0x7FFFFFFFu) : ~key;
  float thr = __uint_as_float(fb);
  for (int i = tid; i < L; i += 256) {
    bool lm = (lmbits[i >> 5] >> (i & 31)) & 1u;
    keep[i] = ((pred[i] > thr) || lm) ? 1 : 0;
  }
}

// ------- Kernel 2a: per-target masked argmin over candidate chunks ----------
__global__ __launch_bounds__(64) void k_bwd(
    const float* __restrict__ txyz, const float* __restrict__ cxyz,
    const int* __restrict__ keep, unsigned long long* __restrict__ tmin,
    int N, int L) {
  __shared__ float4 sc[CTI];
  int lane = threadIdx.x;
  int t = blockIdx.x * BT + lane;
  float tx = 0.f, ty = 0.f, tz = 0.f;
  if (t < N) { tx = txyz[3*t]; ty = txyz[3*t+1]; tz = txyz[3*t+2]; }
  int c0 = blockIdx.y * CCH;
  int c1 = min(c0 + CCH, L);
  float best = 3e38f; int bidx = 0;
  for (int tile = c0; tile < c1; tile += CTI) {
    int cnt = min(CTI, c1 - tile);
    for (int j = lane; j < cnt; j += BT) {
      int ci = tile + j;
      sc[j] = make_float4(cxyz[3*ci], cxyz[3*ci+1], cxyz[3*ci+2],
                          keep[ci] ? 1.0f : 0.0f);
    }
    __syncthreads();
    #pragma unroll 4
    for (int c = 0; c < cnt; ++c) {
      float4 cd = sc[c];
      float dx = tx - cd.x, dy = ty - cd.y, dz = tz - cd.z;
      float d = fmaf(dx, dx, fmaf(dy, dy, dz * dz));
      d = (cd.w != 0.f) ? d : 1e30f;   // where(keep, d2, BIG)
      if (d < best) { best = d; bidx = tile + c; }
    }
    __syncthreads();
  }
  if (t < N) {
    unsigned long long pack =
        ((unsigned long long)__float_as_uint(best) << 32) | (unsigned int)bidx;
    atomicMin(&tmin[t], pack);
  }
}

// ------- Kernel 2b: scatter w-weighted colors into num/den ------------------
__global__ __launch_bounds__(64) void k_bwd_scatter(
    const float* __restrict__ trgb, const unsigned long long* __restrict__ tmin,
    float4* __restrict__ numden, int* __restrict__ zerohit,
    float4* __restrict__ zcolor, int N) {
  int t = blockIdx.x * 64 + threadIdx.x;
  if (t >= N) return;
  unsigned long long pack = tmin[t];
  float d = __uint_as_float((unsigned int)(pack >> 32));
  int idx = (int)(pack & 0xFFFFFFFFull);
  float r = trgb[3*t], g = trgb[3*t+1], b = trgb[3*t+2];
  if (d == 0.0f) {
    zerohit[idx] = 1;
    zcolor[idx] = make_float4(r, g, b, 0.f);
  } else {
    float w = 1.0f / sqrtf(fmaxf(d, 1e-30f));
    atomicAdd(&numden[idx].x, r * w);
    atomicAdd(&numden[idx].y, g * w);
    atomicAdd(&numden[idx].z, b * w);
    atomicAdd(&numden[idx].w, w);
  }
}

// ------- Kernel 2c: BCE coord loss + compact empty kept candidates ----------
__global__ __launch_bounds__(256) void k_bce_compact(
    const float* __restrict__ pred, const int* __restrict__ ktgt,
    const int* __restrict__ keep, const float4* __restrict__ numden,
    const int* __restrict__ zerohit, int* __restrict__ elist,
    int* __restrict__ ecount, float* __restrict__ out, int L) {
  int l = blockIdx.x * 256 + threadIdx.x;
  float term = 0.f;
  if (l < L) {
    float p = pred[l];
    float t = (float)ktgt[l];
    term = fmaxf(p, 0.f) - p * t + log1pf(expf(-fabsf(p)));
    bool empty = keep[l] && (numden[l].w == 0.f) && (zerohit[l] == 0);
    if (empty) {
      int pos = atomicAdd(ecount, 1);
      elist[pos] = l;
    }
  }
  for (int off = 32; off > 0; off >>= 1) term += __shfl_down(term, off);
  if ((threadIdx.x & 63) == 0) atomicAdd(&out[0], term);
}

// ------- Kernel 3a: forward argmin (empties only) over target chunks --------
__global__ __launch_bounds__(64) void k_fwd(
    const float* __restrict__ txyz, const float* __restrict__ cxyz,
    const int* __restrict__ elist, const int* __restrict__ ecount,
    unsigned long long* __restrict__ fmin, int N) {
  int ec = ecount[0];
  if ((int)(blockIdx.x * ET) >= ec) return;   // uniform early-exit
  __shared__ float4 st[TTI];
  int lane = threadIdx.x;
  int e = blockIdx.x * ET + lane;
  bool act = e < ec;
  int l = act ? elist[e] : 0;
  float cx = 0.f, cy = 0.f, cz = 0.f;
  if (act) { cx = cxyz[3*l]; cy = cxyz[3*l+1]; cz = cxyz[3*l+2]; }
  int t0 = blockIdx.y * TCH;
  int t1 = min(t0 + TCH, N);
  float best = 3e38f; int bidx = 0;
  for (int tile = t0; tile < t1; tile += TTI) {
    int cnt = min(TTI, t1 - tile);
    for (int j = lane; j < cnt; j += ET) {
      int ti = tile + j;
      st[j] = make_float4(txyz[3*ti], txyz[3*ti+1], txyz[3*ti+2], 0.f);
    }
    __syncthreads();
    #pragma unroll 4
    for (int c = 0; c < cnt; ++c) {
      float4 td = st[c];
      float dx = cx - td.x, dy = cy - td.y, dz = cz - td.z;
      float d = fmaf(dx, dx, fmaf(dy, dy, dz * dz));
      if (d < best) { best = d; bidx = tile + c; }
    }
    __syncthreads();
  }
  if (act) {
    unsigned long long pack =
        ((unsigned long long)__float_as_uint(best) << 32) | (unsigned int)bidx;
    atomicMin(&fmin[l], pack);
  }
}

// ------- Kernel 3b: final recolor select + L1 loss --------------------------
__global__ __launch_bounds__(256) void k_loss(
    const float* __restrict__ crgb, const float* __restrict__ trgb,
    const int* __restrict__ keep, const float4* __restrict__ numden,
    const int* __restrict__ zerohit, const float4* __restrict__ zcolor,
    const unsigned long long* __restrict__ fmin,
    float* __restrict__ out, int L) {
  int l = blockIdx.x * 256 + threadIdx.x;
  float loss = 0.f;
  if (l < L && keep[l]) {
    float rr, rg, rb;
    if (zerohit[l]) {
      float4 z = zcolor[l]; rr = z.x; rg = z.y; rb = z.z;
    } else {
      float4 nd = numden[l];
      if (nd.w != 0.f) { rr = nd.x / nd.w; rg = nd.y / nd.w; rb = nd.z / nd.w; }
      else {
        int ti = (int)(fmin[l] & 0xFFFFFFFFull);
        rr = trgb[3*ti]; rg = trgb[3*ti+1]; rb = trgb[3*ti+2];
      }
    }
    float sr = crgb[3*l] * 255.f, sg = crgb[3*l+1] * 255.f, sb = crgb[3*l+2] * 255.f;
    loss = fabsf(sr - rr) + fabsf(sg - rg) + fabsf(sb - rb);
  }
  for (int off = 32; off > 0; off >>= 1) loss += __shfl_down(loss, off);
  if ((threadIdx.x & 63) == 0) atomicAdd(&out[1], loss);
}

extern "C" void kernel_launch(void* const* d_in, const int* in_sizes, int n_in,
                              void* d_out, int out_size, void* d_ws, size_t ws_size,
                              hipStream_t stream) {
  const float* pred = (const float*)d_in[0];
  const float* cxyz = (const float*)d_in[1];
  const float* crgb = (const float*)d_in[2];
  const float* txyz = (const float*)d_in[3];
  const float* trgb = (const float*)d_in[4];
  const int*   ktgt = (const int*)d_in[5];
  const int*   pnum = (const int*)d_in[6];
  int L = in_sizes[0];
  int N = in_sizes[3] / 3;
  int nb_t = (N + BT - 1) / BT;

  // workspace layout (all 16B-friendly offsets)
  char* ws = (char*)d_ws;
  size_t off = 0;
  int* keep = (int*)(ws + off);                      off += (size_t)L * 4;
  float4* numden = (float4*)(ws + off);              off += (size_t)L * 16;
  int* zerohit = (int*)(ws + off);                   off += (size_t)L * 4;
  float4* zcolor = (float4*)(ws + off);              off += (size_t)L * 16;
  unsigned long long* tmin = (unsigned long long*)(ws + off); off += (size_t)nb_t * BT * 8;
  unsigned long long* fmin = (unsigned long long*)(ws + off); off += (size_t)L * 8;
  int* elist = (int*)(ws + off);                     off += (size_t)L * 4;
  int* ecount = (int*)(ws + off);                    off += 256;

  float* out = (float*)d_out;
  hipMemsetAsync(out, 0, 2 * sizeof(float), stream);
  hipMemsetAsync(numden, 0, (size_t)L * 16, stream);
  hipMemsetAsync(zerohit, 0, (size_t)L * 4, stream);
  hipMemsetAsync(tmin, 0xFF, (size_t)nb_t * BT * 8, stream);
  hipMemsetAsync(fmin, 0xFF, (size_t)L * 8, stream);
  hipMemsetAsync(ecount, 0, sizeof(int), stream);

  k_keep<<<1, 256, 0, stream>>>(pred, pnum, keep, L);

  dim3 g2(nb_t, (L + CCH - 1) / CCH);
  k_bwd<<<g2, BT, 0, stream>>>(txyz, cxyz, keep, tmin, N, L);

  k_bwd_scatter<<<nb_t, BT, 0, stream>>>(trgb, tmin, numden, zerohit, zcolor, N);

  k_bce_compact<<<(L + 255) / 256, 256, 0, stream>>>(
      pred, ktgt, keep, numden, zerohit, elist, ecount, out, L);

  dim3 g3((L + ET - 1) / ET, (N + TCH - 1) / TCH);
  k_fwd<<<g3, ET, 0, stream>>>(txyz, cxyz, elist, ecount, fmin, N);

  k_loss<<<(L + 255) / 256, 256, 0, stream>>>(
      crgb, trgb, keep, numden, zerohit, zcolor, fmin, out, L);
}

// Round 2
// 246.286 us; speedup vs baseline: 1.2847x; 1.2847x over previous
//
#include <hip/hip_runtime.h>
#include <hip/hip_bf16.h>

// Decoder loss: keep-mask (kth-value threshold + local max), BCE coord loss,
// bidirectional NN recolor + L1 rgb loss.
// L = 16384 candidates, N = 10000 targets, K=8 (collapses to argmin).
// R2: compacted kept-candidate list, expansion-form argmin (3 FMA/cand),
//     256-thread scan blocks, fused init kernel.

#define SCAN_T 256   // threads per scan block
#define BCH 512      // kept-candidate chunk per blockIdx.y in k_bwd
#define FCH 512      // target chunk per blockIdx.y in k_fwd

// ---------------- Kernel 0: fused init (replaces 6 memsets) -----------------
__global__ __launch_bounds__(256) void k_init(
    const float* __restrict__ txyz, float4* __restrict__ ttile,
    float4* __restrict__ numden, int* __restrict__ zerohit,
    unsigned long long* __restrict__ tmin, unsigned long long* __restrict__ fmin,
    int* __restrict__ counters, float* __restrict__ out, int L, int N) {
  int i = blockIdx.x * 256 + threadIdx.x;
  if (i < N) {
    float x = txyz[3*i], y = txyz[3*i+1], z = txyz[3*i+2];
    ttile[i] = make_float4(x, y, z, fmaf(x, x, fmaf(y, y, z * z)));
    tmin[i] = ~0ull;
  }
  if (i < L) {
    numden[i] = make_float4(0.f, 0.f, 0.f, 0.f);
    zerohit[i] = 0;
    fmin[i] = ~0ull;
  }
  if (i < 2) { counters[i] = 0; out[i] = 0.f; }
}

// ------- Kernel 1: keep mask (local max + exact rank select) + compaction ---
__global__ __launch_bounds__(256) void k_keep(
    const float* __restrict__ pred, const int* __restrict__ pnum_p,
    const float* __restrict__ cxyz, int* __restrict__ keep,
    float4* __restrict__ klist, int* __restrict__ kidx,
    int* __restrict__ counters, int L) {
  __shared__ unsigned int lmbits[512];   // L/32 bits, L<=16384
  __shared__ unsigned int hist[256];
  __shared__ unsigned int sel_prefix;
  __shared__ unsigned int sel_rank;
  int tid = threadIdx.x;
  int words = L / 32;
  // per-8-group argmax (first occurrence, matching jnp.argmax)
  for (int w = tid; w < words; w += 256) {
    unsigned int bits = 0;
    for (int g = 0; g < 4; ++g) {
      int base = w * 32 + g * 8;
      float bv = pred[base]; int bi = 0;
      for (int j = 1; j < 8; ++j) {
        float v = pred[base + j];
        if (v > bv) { bv = v; bi = j; }
      }
      bits |= 1u << (g * 8 + bi);
    }
    lmbits[w] = bits;
  }
  if (tid == 0) { sel_prefix = 0u; sel_rank = 0u; }
  __syncthreads();
  int rank = L - pnum_p[0] - 1;   // 0-based rank of threshold element
  // 4-round radix select on monotone uint keys (local-max -> +inf)
  for (int shift = 24; shift >= 0; shift -= 8) {
    for (int b = tid; b < 256; b += 256) hist[b] = 0u;
    __syncthreads();
    unsigned int mask_hi = (shift == 24) ? 0u : (0xFFFFFFFFu << (shift + 8));
    unsigned int pfx = sel_prefix;
    for (int i = tid; i < L; i += 256) {
      bool lm = (lmbits[i >> 5] >> (i & 31)) & 1u;
      unsigned int key;
      if (lm) key = 0xFF800000u;   // map(+inf)
      else {
        unsigned int fb = __float_as_uint(pred[i]);
        key = (fb & 0x80000000u) ? ~fb : (fb | 0x80000000u);
      }
      if ((key & mask_hi) == (pfx & mask_hi))
        atomicAdd(&hist[(key >> shift) & 255u], 1u);
    }
    __syncthreads();
    if (tid == 0) {
      unsigned int r = (shift == 24) ? (unsigned int)rank : sel_rank;
      unsigned int cum = 0, chosen = 0;
      for (int b = 0; b < 256; ++b) {
        unsigned int c = hist[b];
        if (r < cum + c) { chosen = (unsigned int)b; r -= cum; break; }
        cum += c;
      }
      sel_prefix |= chosen << shift;
      sel_rank = r;
    }
    __syncthreads();
  }
  unsigned int key = sel_prefix;
  unsigned int fb = (key & 0x80000000u) ? (key & 0x7FFFFFFFu) : ~key;
  float thr = __uint_as_float(fb);
  for (int i = tid; i < L; i += 256) {
    bool lm = (lmbits[i >> 5] >> (i & 31)) & 1u;
    bool kp = (pred[i] > thr) || lm;
    keep[i] = kp ? 1 : 0;
    if (kp) {
      int pos = atomicAdd(&counters[0], 1);   // order irrelevant (no ties)
      float x = cxyz[3*i], y = cxyz[3*i+1], z = cxyz[3*i+2];
      klist[pos] = make_float4(x, y, z, fmaf(x, x, fmaf(y, y, z * z)));
      kidx[pos] = i;
    }
  }
}

// ------- Kernel 2a: per-target argmin over compacted kept candidates --------
__global__ __launch_bounds__(SCAN_T) void k_bwd(
    const float* __restrict__ txyz, const float4* __restrict__ klist,
    const int* __restrict__ kidx, const int* __restrict__ counters,
    unsigned long long* __restrict__ tmin, int N) {
  int kc = counters[0];
  int c0 = blockIdx.y * BCH;
  if (c0 >= kc) return;                 // uniform early-exit
  int c1 = min(c0 + BCH, kc);
  __shared__ float4 sc[SCAN_T];
  int tid = threadIdx.x;
  int t = blockIdx.x * SCAN_T + tid;
  float tx = 0.f, ty = 0.f, tz = 0.f;
  if (t < N) { tx = txyz[3*t]; ty = txyz[3*t+1]; tz = txyz[3*t+2]; }
  float ntx = -2.f * tx, nty = -2.f * ty, ntz = -2.f * tz;
  float best = 3e38f; int bpos = -1;
  for (int tile = c0; tile < c1; tile += SCAN_T) {
    int cnt = min(SCAN_T, c1 - tile);
    if (tid < cnt) sc[tid] = klist[tile + tid];
    __syncthreads();
    #pragma unroll 8
    for (int c = 0; c < cnt; ++c) {
      float4 cd = sc[c];
      // monotone surrogate: |c|^2 - 2 t.c  (argmin-equivalent to |t-c|^2)
      float d = fmaf(ntx, cd.x, cd.w);
      d = fmaf(nty, cd.y, d);
      d = fmaf(ntz, cd.z, d);
      if (d < best) { best = d; bpos = tile + c; }
    }
    __syncthreads();
  }
  if (t < N && bpos >= 0) {
    float4 cd = klist[bpos];
    float dx = tx - cd.x, dy = ty - cd.y, dz = tz - cd.z;
    float dtrue = fmaf(dx, dx, fmaf(dy, dy, dz * dz));  // exact formula (R1-proven)
    unsigned long long pack =
        ((unsigned long long)__float_as_uint(dtrue) << 32) |
        (unsigned int)kidx[bpos];
    atomicMin(&tmin[t], pack);
  }
}

// ------- Kernel 2b: scatter w-weighted colors into num/den ------------------
__global__ __launch_bounds__(256) void k_bwd_scatter(
    const float* __restrict__ trgb, const unsigned long long* __restrict__ tmin,
    float4* __restrict__ numden, int* __restrict__ zerohit,
    float4* __restrict__ zcolor, int N) {
  int t = blockIdx.x * 256 + threadIdx.x;
  if (t >= N) return;
  unsigned long long pack = tmin[t];
  float d = __uint_as_float((unsigned int)(pack >> 32));
  int idx = (int)(pack & 0xFFFFFFFFull);
  float r = trgb[3*t], g = trgb[3*t+1], b = trgb[3*t+2];
  if (d == 0.0f) {
    zerohit[idx] = 1;
    zcolor[idx] = make_float4(r, g, b, 0.f);
  } else {
    float w = 1.0f / sqrtf(fmaxf(d, 1e-30f));
    atomicAdd(&numden[idx].x, r * w);
    atomicAdd(&numden[idx].y, g * w);
    atomicAdd(&numden[idx].z, b * w);
    atomicAdd(&numden[idx].w, w);
  }
}

// ------- Kernel 2c: BCE coord loss + compact empty kept candidates ----------
__global__ __launch_bounds__(256) void k_bce_compact(
    const float* __restrict__ pred, const int* __restrict__ ktgt,
    const int* __restrict__ keep, const float4* __restrict__ numden,
    const int* __restrict__ zerohit, int* __restrict__ elist,
    int* __restrict__ counters, float* __restrict__ out, int L) {
  int l = blockIdx.x * 256 + threadIdx.x;
  float term = 0.f;
  if (l < L) {
    float p = pred[l];
    float t = (float)ktgt[l];
    term = fmaxf(p, 0.f) - p * t + log1pf(expf(-fabsf(p)));
    bool empty = keep[l] && (numden[l].w == 0.f) && (zerohit[l] == 0);
    if (empty) {
      int pos = atomicAdd(&counters[1], 1);
      elist[pos] = l;
    }
  }
  for (int off = 32; off > 0; off >>= 1) term += __shfl_down(term, off);
  if ((threadIdx.x & 63) == 0) atomicAdd(&out[0], term);
}

// ------- Kernel 3a: forward argmin (empties only) over target chunks --------
__global__ __launch_bounds__(SCAN_T) void k_fwd(
    const float4* __restrict__ ttile, const float* __restrict__ cxyz,
    const int* __restrict__ elist, const int* __restrict__ counters,
    unsigned long long* __restrict__ fmin, int N) {
  int ec = counters[1];
  if ((int)(blockIdx.x * SCAN_T) >= ec) return;   // uniform early-exit
  __shared__ float4 st[SCAN_T];
  int tid = threadIdx.x;
  int e = blockIdx.x * SCAN_T + tid;
  bool act = e < ec;
  int l = act ? elist[e] : 0;
  float cx = 0.f, cy = 0.f, cz = 0.f;
  if (act) { cx = cxyz[3*l]; cy = cxyz[3*l+1]; cz = cxyz[3*l+2]; }
  float ncx = -2.f * cx, ncy = -2.f * cy, ncz = -2.f * cz;
  float c2 = fmaf(cx, cx, fmaf(cy, cy, cz * cz));
  int t0 = blockIdx.y * FCH;
  int t1 = min(t0 + FCH, N);
  float best = 3e38f; int bidx = 0;
  for (int tile = t0; tile < t1; tile += SCAN_T) {
    int cnt = min(SCAN_T, t1 - tile);
    if (tid < cnt) st[tid] = ttile[tile + tid];
    __syncthreads();
    #pragma unroll 8
    for (int c = 0; c < cnt; ++c) {
      float4 td = st[c];
      float d = fmaf(ncx, td.x, td.w);
      d = fmaf(ncy, td.y, d);
      d = fmaf(ncz, td.z, d);
      if (d < best) { best = d; bidx = tile + c; }
    }
    __syncthreads();
  }
  if (act) {
    float dkey = fmaxf(best + c2, 0.f);   // consistent merge key across chunks
    unsigned long long pack =
        ((unsigned long long)__float_as_uint(dkey) << 32) | (unsigned int)bidx;
    atomicMin(&fmin[l], pack);
  }
}

// ------- Kernel 3b: final recolor select + L1 loss --------------------------
__global__ __launch_bounds__(256) void k_loss(
    const float* __restrict__ crgb, const float* __restrict__ trgb,
    const int* __restrict__ keep, const float4* __restrict__ numden,
    const int* __restrict__ zerohit, const float4* __restrict__ zcolor,
    const unsigned long long* __restrict__ fmin,
    float* __restrict__ out, int L) {
  int l = blockIdx.x * 256 + threadIdx.x;
  float loss = 0.f;
  if (l < L && keep[l]) {
    float rr, rg, rb;
    if (zerohit[l]) {
      float4 z = zcolor[l]; rr = z.x; rg = z.y; rb = z.z;
    } else {
      float4 nd = numden[l];
      if (nd.w != 0.f) { rr = nd.x / nd.w; rg = nd.y / nd.w; rb = nd.z / nd.w; }
      else {
        int ti = (int)(fmin[l] & 0xFFFFFFFFull);
        rr = trgb[3*ti]; rg = trgb[3*ti+1]; rb = trgb[3*ti+2];
      }
    }
    float sr = crgb[3*l] * 255.f, sg = crgb[3*l+1] * 255.f, sb = crgb[3*l+2] * 255.f;
    loss = fabsf(sr - rr) + fabsf(sg - rg) + fabsf(sb - rb);
  }
  for (int off = 32; off > 0; off >>= 1) loss += __shfl_down(loss, off);
  if ((threadIdx.x & 63) == 0) atomicAdd(&out[1], loss);
}

extern "C" void kernel_launch(void* const* d_in, const int* in_sizes, int n_in,
                              void* d_out, int out_size, void* d_ws, size_t ws_size,
                              hipStream_t stream) {
  const float* pred = (const float*)d_in[0];
  const float* cxyz = (const float*)d_in[1];
  const float* crgb = (const float*)d_in[2];
  const float* txyz = (const float*)d_in[3];
  const float* trgb = (const float*)d_in[4];
  const int*   ktgt = (const int*)d_in[5];
  const int*   pnum = (const int*)d_in[6];
  int L = in_sizes[0];
  int N = in_sizes[3] / 3;

  // workspace layout (16B-aligned chunks)
  char* ws = (char*)d_ws;
  size_t off = 0;
  int* keep = (int*)(ws + off);                      off += (size_t)L * 4;
  float4* klist = (float4*)(ws + off);               off += (size_t)L * 16;
  int* kidx = (int*)(ws + off);                      off += (size_t)L * 4;
  float4* ttile = (float4*)(ws + off);               off += (size_t)((N + 3) & ~3) * 16;
  float4* numden = (float4*)(ws + off);              off += (size_t)L * 16;
  int* zerohit = (int*)(ws + off);                   off += (size_t)L * 4;
  float4* zcolor = (float4*)(ws + off);              off += (size_t)L * 16;
  unsigned long long* tmin = (unsigned long long*)(ws + off); off += (size_t)((N + 1) & ~1) * 8;
  unsigned long long* fmin = (unsigned long long*)(ws + off); off += (size_t)L * 8;
  int* elist = (int*)(ws + off);                     off += (size_t)L * 4;
  int* counters = (int*)(ws + off);                  off += 256; // [0]=kcount [1]=ecount

  float* out = (float*)d_out;
  int mx = max(L, N);

  k_init<<<(mx + 255) / 256, 256, 0, stream>>>(
      txyz, ttile, numden, zerohit, tmin, fmin, counters, out, L, N);

  k_keep<<<1, 256, 0, stream>>>(pred, pnum, cxyz, keep, klist, kidx, counters, L);

  dim3 g2((N + SCAN_T - 1) / SCAN_T, (L + BCH - 1) / BCH);
  k_bwd<<<g2, SCAN_T, 0, stream>>>(txyz, klist, kidx, counters, tmin, N);

  k_bwd_scatter<<<(N + 255) / 256, 256, 0, stream>>>(
      trgb, tmin, numden, zerohit, zcolor, N);

  k_bce_compact<<<(L + 255) / 256, 256, 0, stream>>>(
      pred, ktgt, keep, numden, zerohit, elist, counters, out, L);

  dim3 g3((L + SCAN_T - 1) / SCAN_T, (N + FCH - 1) / FCH);
  k_fwd<<<g3, SCAN_T, 0, stream>>>(ttile, cxyz, elist, counters, fmin, N);

  k_loss<<<(L + 255) / 256, 256, 0, stream>>>(
      crgb, trgb, keep, numden, zerohit, zcolor, fmin, out, L);
}

// Round 3
// 164.193 us; speedup vs baseline: 1.9271x; 1.5000x over previous
//
#include <hip/hip_runtime.h>
#include <hip/hip_bf16.h>

// Decoder loss: keep-mask (kth-value threshold + local max), BCE coord loss,
// bidirectional NN recolor + L1 rgb loss.
// L = 16384 candidates, N = 10000 targets, K=8 (collapses to argmin).
// R3: parallel rank-select (multi-block hist + one-block in-LDS radix),
//     replacing the 120us single-block k_keep.

#define SCAN_T 256   // threads per scan block
#define BCH 512      // kept-candidate chunk per blockIdx.y in k_bwd
#define FCH 512      // target chunk per blockIdx.y in k_fwd

// ---------------- Kernel 0: init (zeros everything incl. ghist) -------------
__global__ __launch_bounds__(256) void k_init(
    const float* __restrict__ txyz, float4* __restrict__ ttile,
    float4* __restrict__ numden, int* __restrict__ zerohit,
    unsigned long long* __restrict__ tmin, unsigned long long* __restrict__ fmin,
    unsigned int* __restrict__ ghist, int* __restrict__ counters,
    float* __restrict__ out, int L, int N) {
  int i = blockIdx.x * 256 + threadIdx.x;
  if (i < N) {
    float x = txyz[3*i], y = txyz[3*i+1], z = txyz[3*i+2];
    ttile[i] = make_float4(x, y, z, fmaf(x, x, fmaf(y, y, z * z)));
    tmin[i] = ~0ull;
  }
  if (i < L) {
    numden[i] = make_float4(0.f, 0.f, 0.f, 0.f);
    zerohit[i] = 0;
    fmin[i] = ~0ull;
  }
  if (i < 2048) ghist[i] = 0u;
  if (i < 8) counters[i] = 0;
  if (i < 2) out[i] = 0.f;
}

// ------- Kernel 1a: local-max + monotone keys + global 2048-bin hist --------
__global__ __launch_bounds__(256) void k_prep(
    const float* __restrict__ pred, unsigned int* __restrict__ key,
    unsigned char* __restrict__ islm, unsigned int* __restrict__ ghist, int L) {
  __shared__ float sp[256];
  __shared__ unsigned char fl[256];
  __shared__ unsigned int lh[2048];
  int tid = threadIdx.x;
  int i = blockIdx.x * 256 + tid;
  sp[tid] = (i < L) ? pred[i] : -3e38f;
  fl[tid] = 0;
  for (int b = tid; b < 2048; b += 256) lh[b] = 0u;
  __syncthreads();
  if (tid < 32) {   // 32 groups of 8 per block; first-occurrence argmax
    int base = tid * 8;
    float bv = sp[base]; int bi = 0;
    #pragma unroll
    for (int j = 1; j < 8; ++j) {
      float v = sp[base + j];
      if (v > bv) { bv = v; bi = j; }
    }
    fl[base + bi] = 1;
  }
  __syncthreads();
  if (i < L) {
    unsigned char lm = fl[tid];
    unsigned int fb = __float_as_uint(sp[tid]);
    unsigned int k = lm ? 0xFF800000u   // map(+inf)
                        : ((fb & 0x80000000u) ? ~fb : (fb | 0x80000000u));
    key[i] = k;
    islm[i] = lm;
    atomicAdd(&lh[k >> 21], 1u);
  }
  __syncthreads();
  for (int b = tid; b < 2048; b += 256) {
    unsigned int c = lh[b];
    if (c) atomicAdd(&ghist[b], c);
  }
}

// ------- Kernel 1b: exact rank-select (one block; wave-scan + in-LDS radix) -
__global__ __launch_bounds__(256) void k_sel(
    const unsigned int* __restrict__ key, const unsigned int* __restrict__ ghist,
    const int* __restrict__ pnum_p, float* __restrict__ thr_out, int L) {
  __shared__ unsigned int buf[16384];
  __shared__ unsigned int hist[256];
  __shared__ unsigned int sB, sR, sM;
  int tid = threadIdx.x;
  unsigned int rank = (unsigned int)(L - pnum_p[0] - 1);
  if (tid == 0) sM = 0u;
  // --- find top-11-bit bin containing rank (wave 0 only) ---
  if (tid < 64) {
    unsigned int sum = 0;
    #pragma unroll 4
    for (int j = 0; j < 32; ++j) sum += ghist[tid * 32 + j];
    unsigned int incl = sum;
    for (int o = 1; o < 64; o <<= 1) {
      unsigned int v = __shfl_up(incl, o);
      if (tid >= o) incl += v;
    }
    unsigned int excl = incl - sum;
    bool cond = (rank >= excl) && (rank < incl);
    unsigned long long bal = __ballot(cond);
    int first = __ffsll((long long)bal) - 1;
    if (tid == first) {
      unsigned int r = rank - excl, cum = 0;
      for (int j = 0; j < 32; ++j) {
        unsigned int c = ghist[tid * 32 + j];
        if (r < cum + c) { sB = (unsigned int)(tid * 32 + j); sR = r - cum; break; }
        cum += c;
      }
    }
  }
  __syncthreads();
  unsigned int B = sB;
  // --- gather all keys in bin B into LDS (one sweep) ---
  for (int i = tid; i < L; i += 256) {
    unsigned int k = key[i];
    if ((k >> 21) == B) { unsigned int p = atomicAdd(&sM, 1u); buf[p] = k; }
  }
  __syncthreads();
  unsigned int M = sM;
  unsigned int pfx = B << 21;
  const int shifts[3] = {13, 5, 0};
  const unsigned int masks[3] = {0xFFE00000u, 0xFFFFE000u, 0xFFFFFFE0u};
  const int nbs[3] = {256, 256, 32};
  for (int p = 0; p < 3; ++p) {
    hist[tid & 255] = 0u;
    __syncthreads();
    unsigned int mk = masks[p]; int sh = shifts[p]; int nb = nbs[p];
    unsigned int pm = pfx & mk;
    for (unsigned int j = tid; j < M; j += 256) {
      unsigned int k = buf[j];
      if ((k & mk) == pm) atomicAdd(&hist[(k >> sh) & (unsigned)(nb - 1)], 1u);
    }
    __syncthreads();
    if (tid < 64) {
      int g = nb >> 6; if (g < 1) g = 1;
      unsigned int sum = 0;
      for (int j = 0; j < g; ++j) {
        int idx = tid * g + j;
        if (idx < nb) sum += hist[idx];
      }
      unsigned int incl = sum;
      for (int o = 1; o < 64; o <<= 1) {
        unsigned int v = __shfl_up(incl, o);
        if (tid >= o) incl += v;
      }
      unsigned int excl = incl - sum;
      unsigned int r = sR;
      bool cond = (r >= excl) && (r < incl);
      unsigned long long bal = __ballot(cond);
      int first = __ffsll((long long)bal) - 1;
      if (tid == first) {
        unsigned int rr = r - excl, cum = 0;
        for (int j = 0; j < g; ++j) {
          int idx = tid * g + j;
          if (idx >= nb) break;
          unsigned int c = hist[idx];
          if (rr < cum + c) { sB = (unsigned int)idx; sR = rr - cum; break; }
          cum += c;
        }
      }
    }
    __syncthreads();
    pfx |= sB << sh;
    __syncthreads();
  }
  if (tid == 0) {
    unsigned int kk = pfx;
    unsigned int fb = (kk & 0x80000000u) ? (kk & 0x7FFFFFFFu) : ~kk;
    thr_out[0] = __uint_as_float(fb);
  }
}

// ------- Kernel 1c: keep mask + compaction + BCE (fused, multi-block) -------
__global__ __launch_bounds__(256) void k_keepc(
    const float* __restrict__ pred, const unsigned char* __restrict__ islm,
    const float* __restrict__ thr_p, const float* __restrict__ cxyz,
    const int* __restrict__ ktgt, int* __restrict__ keep,
    float4* __restrict__ klist, int* __restrict__ kidx,
    int* __restrict__ counters, float* __restrict__ out, int L) {
  int i = blockIdx.x * 256 + threadIdx.x;
  float thr = thr_p[0];
  float term = 0.f;
  if (i < L) {
    float p = pred[i];
    bool kp = (p > thr) || islm[i];
    keep[i] = kp ? 1 : 0;
    if (kp) {
      int pos = atomicAdd(&counters[0], 1);   // order irrelevant (no ties)
      float x = cxyz[3*i], y = cxyz[3*i+1], z = cxyz[3*i+2];
      klist[pos] = make_float4(x, y, z, fmaf(x, x, fmaf(y, y, z * z)));
      kidx[pos] = i;
    }
    float t = (float)ktgt[i];
    term = fmaxf(p, 0.f) - p * t + log1pf(expf(-fabsf(p)));
  }
  for (int off = 32; off > 0; off >>= 1) term += __shfl_down(term, off);
  if ((threadIdx.x & 63) == 0) atomicAdd(&out[0], term);
}

// ------- Kernel 2a: per-target argmin over compacted kept candidates --------
__global__ __launch_bounds__(SCAN_T) void k_bwd(
    const float* __restrict__ txyz, const float4* __restrict__ klist,
    const int* __restrict__ kidx, const int* __restrict__ counters,
    unsigned long long* __restrict__ tmin, int N) {
  int kc = counters[0];
  int c0 = blockIdx.y * BCH;
  if (c0 >= kc) return;                 // uniform early-exit
  int c1 = min(c0 + BCH, kc);
  __shared__ float4 sc[SCAN_T];
  int tid = threadIdx.x;
  int t = blockIdx.x * SCAN_T + tid;
  float tx = 0.f, ty = 0.f, tz = 0.f;
  if (t < N) { tx = txyz[3*t]; ty = txyz[3*t+1]; tz = txyz[3*t+2]; }
  float ntx = -2.f * tx, nty = -2.f * ty, ntz = -2.f * tz;
  float best = 3e38f; int bpos = -1;
  for (int tile = c0; tile < c1; tile += SCAN_T) {
    int cnt = min(SCAN_T, c1 - tile);
    if (tid < cnt) sc[tid] = klist[tile + tid];
    __syncthreads();
    #pragma unroll 8
    for (int c = 0; c < cnt; ++c) {
      float4 cd = sc[c];
      // monotone surrogate: |c|^2 - 2 t.c  (argmin-equivalent to |t-c|^2)
      float d = fmaf(ntx, cd.x, cd.w);
      d = fmaf(nty, cd.y, d);
      d = fmaf(ntz, cd.z, d);
      if (d < best) { best = d; bpos = tile + c; }
    }
    __syncthreads();
  }
  if (t < N && bpos >= 0) {
    float4 cd = klist[bpos];
    float dx = tx - cd.x, dy = ty - cd.y, dz = tz - cd.z;
    float dtrue = fmaf(dx, dx, fmaf(dy, dy, dz * dz));  // exact formula (R1-proven)
    unsigned long long pack =
        ((unsigned long long)__float_as_uint(dtrue) << 32) |
        (unsigned int)kidx[bpos];
    atomicMin(&tmin[t], pack);
  }
}

// ------- Kernel 2b: scatter w-weighted colors into num/den ------------------
__global__ __launch_bounds__(256) void k_bwd_scatter(
    const float* __restrict__ trgb, const unsigned long long* __restrict__ tmin,
    float4* __restrict__ numden, int* __restrict__ zerohit,
    float4* __restrict__ zcolor, int N) {
  int t = blockIdx.x * 256 + threadIdx.x;
  if (t >= N) return;
  unsigned long long pack = tmin[t];
  float d = __uint_as_float((unsigned int)(pack >> 32));
  int idx = (int)(pack & 0xFFFFFFFFull);
  float r = trgb[3*t], g = trgb[3*t+1], b = trgb[3*t+2];
  if (d == 0.0f) {
    zerohit[idx] = 1;
    zcolor[idx] = make_float4(r, g, b, 0.f);
  } else {
    float w = 1.0f / sqrtf(fmaxf(d, 1e-30f));
    atomicAdd(&numden[idx].x, r * w);
    atomicAdd(&numden[idx].y, g * w);
    atomicAdd(&numden[idx].z, b * w);
    atomicAdd(&numden[idx].w, w);
  }
}

// ------- Kernel 2c: compact empty kept candidates ---------------------------
__global__ __launch_bounds__(256) void k_empty(
    const int* __restrict__ keep, const float4* __restrict__ numden,
    const int* __restrict__ zerohit, int* __restrict__ elist,
    int* __restrict__ counters, int L) {
  int l = blockIdx.x * 256 + threadIdx.x;
  if (l < L && keep[l] && (numden[l].w == 0.f) && (zerohit[l] == 0)) {
    int pos = atomicAdd(&counters[1], 1);
    elist[pos] = l;
  }
}

// ------- Kernel 3a: forward argmin (empties only) over target chunks --------
__global__ __launch_bounds__(SCAN_T) void k_fwd(
    const float4* __restrict__ ttile, const float* __restrict__ cxyz,
    const int* __restrict__ elist, const int* __restrict__ counters,
    unsigned long long* __restrict__ fmin, int N) {
  int ec = counters[1];
  if ((int)(blockIdx.x * SCAN_T) >= ec) return;   // uniform early-exit
  __shared__ float4 st[SCAN_T];
  int tid = threadIdx.x;
  int e = blockIdx.x * SCAN_T + tid;
  bool act = e < ec;
  int l = act ? elist[e] : 0;
  float cx = 0.f, cy = 0.f, cz = 0.f;
  if (act) { cx = cxyz[3*l]; cy = cxyz[3*l+1]; cz = cxyz[3*l+2]; }
  float ncx = -2.f * cx, ncy = -2.f * cy, ncz = -2.f * cz;
  float c2 = fmaf(cx, cx, fmaf(cy, cy, cz * cz));
  int t0 = blockIdx.y * FCH;
  int t1 = min(t0 + FCH, N);
  float best = 3e38f; int bidx = 0;
  for (int tile = t0; tile < t1; tile += SCAN_T) {
    int cnt = min(SCAN_T, t1 - tile);
    if (tid < cnt) st[tid] = ttile[tile + tid];
    __syncthreads();
    #pragma unroll 8
    for (int c = 0; c < cnt; ++c) {
      float4 td = st[c];
      float d = fmaf(ncx, td.x, td.w);
      d = fmaf(ncy, td.y, d);
      d = fmaf(ncz, td.z, d);
      if (d < best) { best = d; bidx = tile + c; }
    }
    __syncthreads();
  }
  if (act) {
    float dkey = fmaxf(best + c2, 0.f);   // consistent merge key across chunks
    unsigned long long pack =
        ((unsigned long long)__float_as_uint(dkey) << 32) | (unsigned int)bidx;
    atomicMin(&fmin[l], pack);
  }
}

// ------- Kernel 3b: final recolor select + L1 loss --------------------------
__global__ __launch_bounds__(256) void k_loss(
    const float* __restrict__ crgb, const float* __restrict__ trgb,
    const int* __restrict__ keep, const float4* __restrict__ numden,
    const int* __restrict__ zerohit, const float4* __restrict__ zcolor,
    const unsigned long long* __restrict__ fmin,
    float* __restrict__ out, int L) {
  int l = blockIdx.x * 256 + threadIdx.x;
  float loss = 0.f;
  if (l < L && keep[l]) {
    float rr, rg, rb;
    if (zerohit[l]) {
      float4 z = zcolor[l]; rr = z.x; rg = z.y; rb = z.z;
    } else {
      float4 nd = numden[l];
      if (nd.w != 0.f) { rr = nd.x / nd.w; rg = nd.y / nd.w; rb = nd.z / nd.w; }
      else {
        int ti = (int)(fmin[l] & 0xFFFFFFFFull);
        rr = trgb[3*ti]; rg = trgb[3*ti+1]; rb = trgb[3*ti+2];
      }
    }
    float sr = crgb[3*l] * 255.f, sg = crgb[3*l+1] * 255.f, sb = crgb[3*l+2] * 255.f;
    loss = fabsf(sr - rr) + fabsf(sg - rg) + fabsf(sb - rb);
  }
  for (int off = 32; off > 0; off >>= 1) loss += __shfl_down(loss, off);
  if ((threadIdx.x & 63) == 0) atomicAdd(&out[1], loss);
}

extern "C" void kernel_launch(void* const* d_in, const int* in_sizes, int n_in,
                              void* d_out, int out_size, void* d_ws, size_t ws_size,
                              hipStream_t stream) {
  const float* pred = (const float*)d_in[0];
  const float* cxyz = (const float*)d_in[1];
  const float* crgb = (const float*)d_in[2];
  const float* txyz = (const float*)d_in[3];
  const float* trgb = (const float*)d_in[4];
  const int*   ktgt = (const int*)d_in[5];
  const int*   pnum = (const int*)d_in[6];
  int L = in_sizes[0];
  int N = in_sizes[3] / 3;

  // workspace layout (16B-aligned chunks)
  char* ws = (char*)d_ws;
  size_t off = 0;
  int* keep = (int*)(ws + off);                      off += (size_t)L * 4;
  float4* klist = (float4*)(ws + off);               off += (size_t)L * 16;
  int* kidx = (int*)(ws + off);                      off += (size_t)L * 4;
  float4* ttile = (float4*)(ws + off);               off += (size_t)((N + 3) & ~3) * 16;
  float4* numden = (float4*)(ws + off);              off += (size_t)L * 16;
  int* zerohit = (int*)(ws + off);                   off += (size_t)L * 4;
  float4* zcolor = (float4*)(ws + off);              off += (size_t)L * 16;
  unsigned long long* tmin = (unsigned long long*)(ws + off); off += (size_t)((N + 1) & ~1) * 8;
  unsigned long long* fmin = (unsigned long long*)(ws + off); off += (size_t)L * 8;
  int* elist = (int*)(ws + off);                     off += (size_t)L * 4;
  unsigned int* key = (unsigned int*)(ws + off);     off += (size_t)L * 4;
  unsigned char* islm = (unsigned char*)(ws + off);  off += ((size_t)L + 15) & ~15ull;
  unsigned int* ghist = (unsigned int*)(ws + off);   off += 2048 * 4;
  float* thr_slot = (float*)(ws + off);              off += 16;
  int* counters = (int*)(ws + off);                  off += 256; // [0]=kcount [1]=ecount

  float* out = (float*)d_out;
  int mx = max(L, N);
  int nbL = (L + 255) / 256;

  k_init<<<(mx + 255) / 256, 256, 0, stream>>>(
      txyz, ttile, numden, zerohit, tmin, fmin, ghist, counters, out, L, N);

  k_prep<<<nbL, 256, 0, stream>>>(pred, key, islm, ghist, L);

  k_sel<<<1, 256, 0, stream>>>(key, ghist, pnum, thr_slot, L);

  k_keepc<<<nbL, 256, 0, stream>>>(
      pred, islm, thr_slot, cxyz, ktgt, keep, klist, kidx, counters, out, L);

  dim3 g2((N + SCAN_T - 1) / SCAN_T, (L + BCH - 1) / BCH);
  k_bwd<<<g2, SCAN_T, 0, stream>>>(txyz, klist, kidx, counters, tmin, N);

  k_bwd_scatter<<<(N + 255) / 256, 256, 0, stream>>>(
      trgb, tmin, numden, zerohit, zcolor, N);

  k_empty<<<nbL, 256, 0, stream>>>(keep, numden, zerohit, elist, counters, L);

  dim3 g3((L + SCAN_T - 1) / SCAN_T, (N + FCH - 1) / FCH);
  k_fwd<<<g3, SCAN_T, 0, stream>>>(ttile, cxyz, elist, counters, fmin, N);

  k_loss<<<(L + 255) / 256, 256, 0, stream>>>(
      crgb, trgb, keep, numden, zerohit, zcolor, fmin, out, L);
}